// Round 1
// baseline (401.422 us; speedup 1.0000x reference)
//
#include <hip/hip_runtime.h>

#define NCLS   32
#define SOS    30
#define EOS    31
#define NEGV   (-10000.0f)
#define LOG2E  1.4426950408889634f
#define LN2    0.6931471805599453f

// One lane per (batch, class). Wave = 2 batches. Block 256 = 8 batches.
// log2-domain CRF forward:
//   rel[c] = scaled alpha minus running offset C (group-uniform scalar)
//   e[j] = exp2(rel[j]) broadcast via wave-private LDS row
//   dot_c = sum_j ET[c][j] * e[j]   (ET = exp2(That[c][j] - mT[c]), precomputed)
//   rel_new = feat*LOG2E + mT[c] + log2(dot_c)
// Re-center every 4 steps by lane-0 value; C accumulates the shifts.
__global__ __launch_bounds__(256) void crf_fwd(const float* __restrict__ feats,
                                               const float* __restrict__ mask,
                                               const float* __restrict__ trans,
                                               float* __restrict__ out,
                                               int S, int B) {
    __shared__ float e_sh[8 * NCLS];   // 8 groups/block, wave-private rows

    const int tid = threadIdx.x;
    const int c   = tid & 31;          // class
    const int g   = tid >> 5;          // group in block
    const int b   = blockIdx.x * 8 + g;

    // ---- one-time: transition row c, log2-scaled, row-max-normalized ----
    float Trow[NCLS];
    float mT = -3.4e38f;
    #pragma unroll
    for (int j = 0; j < NCLS; ++j) {
        Trow[j] = trans[c * NCLS + j] * LOG2E;
        mT = fmaxf(mT, Trow[j]);
    }
    float ET[NCLS];
    #pragma unroll
    for (int j = 0; j < NCLS; ++j) ET[j] = exp2f(Trow[j] - mT);
    const float tEOSc = trans[EOS * NCLS + c] * LOG2E;  // T[EOS][c], scaled

    float* esh = &e_sh[g * NCLS];

    // ---- init alpha0 (log2 domain): SOS=0, others = NEG*LOG2E (exp2 -> 0) ----
    float rel = (c == SOS) ? 0.0f : NEGV * LOG2E;
    float C = 0.0f;

    const size_t fstride = (size_t)B * NCLS;
    const float* fbase = feats + (size_t)b * NCLS + c;
    const float* mbase = mask + b;

    // ---- prefetch ring, depth 4 ----
    float fb[4], mb[4];
    #pragma unroll
    for (int i = 0; i < 4; ++i) {
        int tt = (i < S) ? i : (S - 1);
        fb[i] = fbase[(size_t)tt * fstride];
        mb[i] = mbase[(size_t)tt * (size_t)B];
    }

    #pragma unroll 4
    for (int t = 0; t < S; ++t) {
        const int slot = t & 3;
        const float f = fb[slot];
        const float m = mb[slot];
        int tp = t + 4; if (tp > S - 1) tp = S - 1;
        fb[slot] = fbase[(size_t)tp * fstride];
        mb[slot] = mbase[(size_t)tp * (size_t)B];

        // e = exp2(rel), broadcast through wave-private LDS row
        const float e = exp2f(rel);
        esh[c] = e;
        __builtin_amdgcn_wave_barrier();

        const float4* e4 = (const float4*)esh;
        float d0 = 0.f, d1 = 0.f, d2 = 0.f, d3 = 0.f;
        #pragma unroll
        for (int q = 0; q < 8; ++q) {
            const float4 v = e4[q];
            d0 = fmaf(ET[4 * q + 0], v.x, d0);
            d1 = fmaf(ET[4 * q + 1], v.y, d1);
            d2 = fmaf(ET[4 * q + 2], v.z, d2);
            d3 = fmaf(ET[4 * q + 3], v.w, d3);
        }
        __builtin_amdgcn_wave_barrier();

        const float dot = (d0 + d1) + (d2 + d3);
        const float rel_new = fmaf(f, LOG2E, __log2f(dot) + mT);
        // mask blend: new*m + old*(1-m)  (offset C is common, blend is valid)
        rel = fmaf(m, rel_new - rel, rel);

        // periodic re-centering by lane 0 of the 32-group
        if ((t & 3) == 3) {
            const float D = __shfl(rel, 0, 32);
            rel -= D;
            C += D;
        }
    }

    // ---- epilogue: out[b] = ln2 * (C + log2(sum_c 2^(rel[c] + That[EOS][c]))) ----
    float v = exp2f(rel + tEOSc);
    #pragma unroll
    for (int off = 16; off; off >>= 1) v += __shfl_xor(v, off, 32);
    if (c == 0) out[b] = LN2 * (C + __log2f(v));
}

extern "C" void kernel_launch(void* const* d_in, const int* in_sizes, int n_in,
                              void* d_out, int out_size, void* d_ws, size_t ws_size,
                              hipStream_t stream) {
    const float* feats = (const float*)d_in[0];
    const float* mask  = (const float*)d_in[1];
    const float* trans = (const float*)d_in[2];
    float* out = (float*)d_out;

    const int B = out_size;            // batch  (2048)
    const int S = in_sizes[1] / B;     // seq_len (512)

    const int threads = B * NCLS;      // one lane per (batch, class)
    dim3 block(256);
    dim3 grid(threads / 256);
    hipLaunchKernelGGL(crf_fwd, grid, block, 0, stream, feats, mask, trans, out, S, B);
}

// Round 2
// 266.420 us; speedup vs baseline: 1.5067x; 1.5067x over previous
//
#include <hip/hip_runtime.h>

#define NCLS   32
#define SOS    30
#define EOS    31
#define NEGV   (-10000.0f)
#define LOG2E  1.4426950408889634f
#define LN2    0.6931471805599453f

// One lane per (batch, class). Wave = 2 batches. Block 256 = 8 batches.
// log2-domain CRF forward:
//   rel[c] = scaled alpha minus running offset C (group-uniform scalar)
//   e[j] = exp2(rel[j]) broadcast via wave-private LDS row (b128 broadcast reads)
//   dot_c = sum_j ET[c][j] * e[j]   (ET = exp2(That[c][j] - mT[c]), in VGPRs)
//   rel_new = feat*LOG2E + mT[c] + log2(dot_c)
// Re-center every 8 steps by lane-0 value; C accumulates the shifts.
//
// __launch_bounds__(256, 1): grid is 256 blocks on 256 CUs (1 block/CU, 1
// wave/SIMD) so occupancy can't exceed 1 wave/EU anyway — unlock the full
// VGPR budget so ET[32] + the prefetch ring stay register-resident.
// (Round-1 post-mortem: VGPR_Count=36 proved ET[] was demoted to scratch.)
__global__ __launch_bounds__(256, 1) void crf_fwd(const float* __restrict__ feats,
                                                  const float* __restrict__ mask,
                                                  const float* __restrict__ trans,
                                                  float* __restrict__ out,
                                                  int S, int B) {
    __shared__ float e_sh[8 * NCLS];   // 8 groups/block, wave-private rows

    const int tid = threadIdx.x;
    const int c   = tid & 31;          // class
    const int g   = tid >> 5;          // group in block
    const int b   = blockIdx.x * 8 + g;

    // ---- one-time: transition row c, log2-scaled, row-max-normalized ----
    float ET[NCLS];
    float mT = -3.4e38f;
    #pragma unroll
    for (int j = 0; j < NCLS; ++j) {
        ET[j] = trans[c * NCLS + j] * LOG2E;
        mT = fmaxf(mT, ET[j]);
    }
    #pragma unroll
    for (int j = 0; j < NCLS; ++j) ET[j] = __builtin_amdgcn_exp2f(ET[j] - mT);
    const float tEOSc = trans[EOS * NCLS + c] * LOG2E;  // T[EOS][c], scaled

    float* esh = &e_sh[g * NCLS];
    const float4* e4 = (const float4*)esh;

    // ---- init alpha0 (log2 domain): SOS=0, others = NEG*LOG2E (exp2 -> 0) ----
    float rel = (c == SOS) ? 0.0f : NEGV * LOG2E;
    float C = 0.0f;

    const size_t fstride = (size_t)B * NCLS;
    const float* fptr = feats + (size_t)b * NCLS + c;
    const float* mptr = mask + b;

    auto step = [&](float f, float m) {
        const float e = __builtin_amdgcn_exp2f(rel);
        esh[c] = e;
        __builtin_amdgcn_wave_barrier();
        float d0, d1, d2, d3;
        {   // q = 0 peeled: mults instead of fma-with-zero
            const float4 v = e4[0];
            d0 = ET[0] * v.x; d1 = ET[1] * v.y; d2 = ET[2] * v.z; d3 = ET[3] * v.w;
        }
        #pragma unroll
        for (int q = 1; q < 8; ++q) {
            const float4 v = e4[q];
            d0 = fmaf(ET[4 * q + 0], v.x, d0);
            d1 = fmaf(ET[4 * q + 1], v.y, d1);
            d2 = fmaf(ET[4 * q + 2], v.z, d2);
            d3 = fmaf(ET[4 * q + 3], v.w, d3);
        }
        __builtin_amdgcn_wave_barrier();
        const float dot = (d0 + d1) + (d2 + d3);
        const float rel_new = fmaf(f, LOG2E, __builtin_amdgcn_logf(dot) + mT);
        rel = fmaf(m, rel_new - rel, rel);   // mask blend (C offset common, valid)
    };

    float fb[8], mb[8];

    if (S >= 16) {
        #pragma unroll
        for (int i = 0; i < 8; ++i) {
            fb[i] = fptr[(size_t)i * fstride];
            mb[i] = mptr[(size_t)i * (size_t)B];
        }

        int tb = 0;
        // main loop: unconditional prefetch 8 ahead, strength-reduced pointers
        for (; tb + 16 <= S; tb += 8) {
            const float* fpp = fptr + (size_t)(tb + 8) * fstride;
            const float* mpp = mptr + (size_t)(tb + 8) * (size_t)B;
            #pragma unroll
            for (int u = 0; u < 8; ++u) {
                step(fb[u], mb[u]);
                fb[u] = fpp[(size_t)u * fstride];
                mb[u] = mpp[(size_t)u * (size_t)B];
            }
            const float D = __shfl(rel, 0, 32);   // re-center (lane 0 of group)
            rel -= D; C += D;
        }
        // penultimate block: 8 steps with clamped (possibly dead) prefetch
        {
            #pragma unroll
            for (int u = 0; u < 8; ++u) {
                step(fb[u], mb[u]);
                int tp = tb + 8 + u; tp = (tp < S - 1) ? tp : (S - 1);
                fb[u] = fptr[(size_t)tp * fstride];
                mb[u] = mptr[(size_t)tp * (size_t)B];
            }
            const float D = __shfl(rel, 0, 32);
            rel -= D; C += D;
            tb += 8;
        }
        // tail: up to 7 remaining steps, static slots
        #pragma unroll
        for (int u = 0; u < 8; ++u) {
            if (tb + u < S) step(fb[u], mb[u]);
        }
    } else {
        for (int t = 0; t < S; ++t) {
            step(fptr[(size_t)t * fstride], mptr[(size_t)t * (size_t)B]);
        }
    }

    // ---- epilogue: out[b] = ln2 * (C + log2(sum_c 2^(rel[c] + That[EOS][c]))) ----
    float v = __builtin_amdgcn_exp2f(rel + tEOSc);
    #pragma unroll
    for (int off = 16; off; off >>= 1) v += __shfl_xor(v, off, 32);
    if (c == 0) out[b] = LN2 * (C + __builtin_amdgcn_logf(v));
}

extern "C" void kernel_launch(void* const* d_in, const int* in_sizes, int n_in,
                              void* d_out, int out_size, void* d_ws, size_t ws_size,
                              hipStream_t stream) {
    const float* feats = (const float*)d_in[0];
    const float* mask  = (const float*)d_in[1];
    const float* trans = (const float*)d_in[2];
    float* out = (float*)d_out;

    const int B = out_size;            // batch  (2048)
    const int S = in_sizes[1] / B;     // seq_len (512)

    const int threads = B * NCLS;      // one lane per (batch, class)
    dim3 block(256);
    dim3 grid(threads / 256);
    hipLaunchKernelGGL(crf_fwd, grid, block, 0, stream, feats, mask, trans, out, S, B);
}